// Round 16
// baseline (241.904 us; speedup 1.0000x reference)
//
#include <hip/hip_runtime.h>
#include <hip/hip_bf16.h>

typedef __attribute__((ext_vector_type(8))) short short8;
typedef __attribute__((ext_vector_type(4))) float f32x4;
typedef __attribute__((ext_vector_type(4))) int i32x4;

__device__ inline unsigned short f2bs(float f) {
  union { float f; unsigned u; } v; v.f = f;
  unsigned r = v.u + 0x7fff + ((v.u >> 16) & 1);
  return (unsigned short)(r >> 16);
}

__device__ inline float bs2f(unsigned short u) {
  union { unsigned u; float f; } c; c.u = (unsigned)u << 16; return c.f;
}

__device__ inline unsigned pkbf(float a, float b) {
  __hip_bfloat162 h = __float22bfloat162_rn(float2{a, b});
  union { __hip_bfloat162 h; unsigned u; } c; c.h = h;
  return c.u;
}

__device__ inline float exp2v(float x) {
  float r; asm("v_exp_f32 %0, %1" : "=v"(r) : "v"(x)); return r;
}

__device__ inline float max3f(float a, float b, float c) {
  return fmaxf(fmaxf(a, b), c);
}

__device__ inline void gload16(const void* g, void* l) {
  __builtin_amdgcn_global_load_lds((const __attribute__((address_space(1))) void*)g,
                                   (__attribute__((address_space(3))) void*)l,
                                   16, 0, 0);
}

// ---------------- prep: weight cvt (blocks 0..6911) + LN1 (blocks 6912..11007) ----------------
__global__ __launch_bounds__(256)
void prep(const float* __restrict__ s0, const float* __restrict__ s1,
          const float* __restrict__ s2, const float* __restrict__ s3,
          unsigned short* __restrict__ d0, unsigned short* __restrict__ d1,
          unsigned short* __restrict__ d2, unsigned short* __restrict__ d3,
          const float* __restrict__ x, const float* __restrict__ lw,
          const float* __restrict__ lb, unsigned short* __restrict__ out)
{
  if (blockIdx.x < 6912) {
    size_t i = (size_t)blockIdx.x * 256 + threadIdx.x;
    const float* src; unsigned short* dst;
    if (i < 442368) { src = s0; dst = d0; }
    else if (i < 589824) { src = s1; dst = d1; i -= 442368; }
    else if (i < 1179648) { src = s2; dst = d2; i -= 589824; }
    else { src = s3; dst = d3; i -= 1179648; }
    float4 v = ((const float4*)src)[i];
    ushort4 o;
    o.x = f2bs(v.x); o.y = f2bs(v.y); o.z = f2bs(v.z); o.w = f2bs(v.w);
    ((ushort4*)dst)[i] = o;
    return;
  }
  const int row = blockIdx.x - 6912;
  const float* xr = x + (size_t)row * 768;
  float v[3];
  float s = 0.f, sq = 0.f;
#pragma unroll
  for (int i = 0; i < 3; ++i) {
    v[i] = xr[threadIdx.x + i * 256];
    s += v[i]; sq += v[i] * v[i];
  }
#pragma unroll
  for (int d = 1; d < 64; d <<= 1) {
    s  += __shfl_xor(s, d, 64);
    sq += __shfl_xor(sq, d, 64);
  }
  __shared__ float ss[4], ssq[4];
  const int wv = threadIdx.x >> 6;
  if ((threadIdx.x & 63) == 0) { ss[wv] = s; ssq[wv] = sq; }
  __syncthreads();
  s  = ss[0] + ss[1] + ss[2] + ss[3];
  sq = ssq[0] + ssq[1] + ssq[2] + ssq[3];
  const float mu = s * (1.0f / 768.0f);
  const float var = sq * (1.0f / 768.0f) - mu * mu;
  const float rstd = rsqrtf(var + 1e-5f);
#pragma unroll
  for (int i = 0; i < 3; ++i) {
    const int c = threadIdx.x + i * 256;
    out[(size_t)row * 768 + c] = f2bs((v[i] - mu) * rstd * lw[c] + lb[c]);
  }
}

// ---------------- LayerNorm (fallback path only) ----------------
__global__ __launch_bounds__(256)
void ln_kernel(const float* __restrict__ x, const float* __restrict__ w,
               const float* __restrict__ bsh, unsigned short* __restrict__ out)
{
  const int row = blockIdx.x;
  const float* xr = x + (size_t)row * 768;
  float v[3];
  float s = 0.f, sq = 0.f;
#pragma unroll
  for (int i = 0; i < 3; ++i) {
    v[i] = xr[threadIdx.x + i * 256];
    s += v[i]; sq += v[i] * v[i];
  }
#pragma unroll
  for (int d = 1; d < 64; d <<= 1) {
    s  += __shfl_xor(s, d, 64);
    sq += __shfl_xor(sq, d, 64);
  }
  __shared__ float ss[4], ssq[4];
  const int wv = threadIdx.x >> 6;
  if ((threadIdx.x & 63) == 0) { ss[wv] = s; ssq[wv] = sq; }
  __syncthreads();
  s  = ss[0] + ss[1] + ss[2] + ss[3];
  sq = ssq[0] + ssq[1] + ssq[2] + ssq[3];
  const float mu = s * (1.0f / 768.0f);
  const float var = sq * (1.0f / 768.0f) - mu * mu;
  const float rstd = rsqrtf(var + 1e-5f);
#pragma unroll
  for (int i = 0; i < 3; ++i) {
    const int c = threadIdx.x + i * 256;
    out[(size_t)row * 768 + c] = f2bs((v[i] - mu) * rstd * w[c] + bsh[c]);
  }
}

// ---------------- proj reduce (bf16 partials) + residual + LN2 fused ----------------
__global__ __launch_bounds__(256)
void reduce_ln2(const unsigned short* __restrict__ p, const float* __restrict__ bias,
                const float* __restrict__ resid, const float* __restrict__ lw,
                const float* __restrict__ lb, float* __restrict__ x2,
                unsigned short* __restrict__ h)
{
  const size_t MN = 4096ull * 768;
  const int row = blockIdx.x;
  const size_t r0 = (size_t)row * 768;
  float v[3];
  float s = 0.f, sq = 0.f;
#pragma unroll
  for (int i = 0; i < 3; ++i) {
    const int c = threadIdx.x + i * 256;
    const float a = bs2f(p[r0 + c]) + bs2f(p[MN + r0 + c]) + bias[c] + resid[r0 + c];
    x2[r0 + c] = a;
    v[i] = a; s += a; sq += a * a;
  }
#pragma unroll
  for (int d = 1; d < 64; d <<= 1) {
    s  += __shfl_xor(s, d, 64);
    sq += __shfl_xor(sq, d, 64);
  }
  __shared__ float ss[4], ssq[4];
  const int wv = threadIdx.x >> 6;
  if ((threadIdx.x & 63) == 0) { ss[wv] = s; ssq[wv] = sq; }
  __syncthreads();
  s  = ss[0] + ss[1] + ss[2] + ss[3];
  sq = ssq[0] + ssq[1] + ssq[2] + ssq[3];
  const float mu = s * (1.0f / 768.0f);
  const float var = sq * (1.0f / 768.0f) - mu * mu;
  const float rstd = rsqrtf(var + 1e-5f);
#pragma unroll
  for (int i = 0; i < 3; ++i) {
    const int c = threadIdx.x + i * 256;
    h[r0 + c] = f2bs((v[i] - mu) * rstd * lw[c] + lb[c]);
  }
}

// ---------------- split-K reduce (bf16 partials) ----------------
template<int S>
__global__ __launch_bounds__(256)
void reduce_k(const unsigned short* __restrict__ p, const float* __restrict__ bias,
              const float* __restrict__ resid, float* __restrict__ out)
{
  const size_t MN = 4096ull * 768;
  const size_t i = ((size_t)blockIdx.x * 256 + threadIdx.x) * 4;
  float ax = 0.f, ay = 0.f, az = 0.f, aw = 0.f;
#pragma unroll
  for (int s = 0; s < S; ++s) {
    ushort4 b = *(const ushort4*)(p + s * MN + i);
    ax += bs2f(b.x); ay += bs2f(b.y); az += bs2f(b.z); aw += bs2f(b.w);
  }
  const int col = (int)(i % 768);
  float4 bb = *(const float4*)(bias + col);
  float4 rr = *(const float4*)(resid + i);
  float4 r;
  r.x = ax + bb.x + rr.x; r.y = ay + bb.y + rr.y;
  r.z = az + bb.z + rr.z; r.w = aw + bb.w + rr.w;
  *(float4*)(out + i) = r;
}

// ---------------- NT GEMM (r13 chunk-swizzled staging, unchanged) ----------------
template<int EPI>
__global__ __launch_bounds__(256, 3)
void gemm_nt(const unsigned short* __restrict__ A,
             const unsigned short* __restrict__ Bw,
             const float* __restrict__ bias,
             const float* __restrict__ resid,
             void* __restrict__ out0, void* __restrict__ out1, void* __restrict__ out2,
             int M, int N, int Kslice, int Kstride)
{
  __shared__ __align__(16) unsigned short As[3][128 * 32];
  __shared__ __align__(16) unsigned short Bs[3][128 * 32];
  const int tid = threadIdx.x;
  const int lane = tid & 63;
  const int w = tid >> 6;
  const int wr = w >> 1, wc = w & 1;
  const int l15 = lane & 15, g = lane >> 4;

  const int nwg = gridDim.x * gridDim.y;
  const int hw = blockIdx.y * gridDim.x + blockIdx.x;
  const int virt = (hw & 7) * (nwg >> 3) + (hw >> 3);
  const int m0 = (virt / gridDim.x) * 128;
  const int n0 = (virt % gridDim.x) * 128;
  const int kbase = blockIdx.z * Kslice;

  f32x4 acc[4][4];
#pragma unroll
  for (int m = 0; m < 4; ++m)
#pragma unroll
    for (int n = 0; n < 4; ++n)
      acc[m][n] = (f32x4){0.f, 0.f, 0.f, 0.f};

  auto stage = [&](int buf, int k0) {
#pragma unroll
    for (int i = 0; i < 2; ++i) {
      const int f = tid + i * 256;
      const int row = f >> 2, c8 = f & 3;
      const int sc = c8 ^ (row & 3);
      gload16(A  + (size_t)(m0 + row) * Kstride + kbase + k0 + sc * 8, (char*)&As[buf][0] + f * 16);
      gload16(Bw + (size_t)(n0 + row) * Kstride + kbase + k0 + sc * 8, (char*)&Bs[buf][0] + f * 16);
    }
  };

  const int NT = Kslice >> 5;
  stage(0, 0);
  stage(1, 32);

  for (int t = 0; t < NT; ++t) {
    const int buf = t % 3;
    if (t + 1 < NT) {
      asm volatile("s_waitcnt vmcnt(4)" ::: "memory");
    } else {
      asm volatile("s_waitcnt vmcnt(0)" ::: "memory");
    }
    __builtin_amdgcn_s_barrier();
    asm volatile("" ::: "memory");
    if (t + 2 < NT) stage((t + 2) % 3, (t + 2) * 32);

    short8 af[4], bfr[4];
#pragma unroll
    for (int m = 0; m < 4; ++m) {
      const int r = wr * 64 + m * 16 + l15;
      af[m] = *(const short8*)((const char*)&As[buf][0] + ((size_t)r * 32 + (g ^ (r & 3)) * 8) * 2);
    }
#pragma unroll
    for (int n = 0; n < 4; ++n) {
      const int r = wc * 64 + n * 16 + l15;
      bfr[n] = *(const short8*)((const char*)&Bs[buf][0] + ((size_t)r * 32 + (g ^ (r & 3)) * 8) * 2);
    }
#pragma unroll
    for (int m = 0; m < 4; ++m)
#pragma unroll
      for (int n = 0; n < 4; ++n)
        acc[m][n] = __builtin_amdgcn_mfma_f32_16x16x32_bf16(af[m], bfr[n], acc[m][n], 0, 0, 0);
    asm volatile("" ::: "memory");
  }

  // epilogue: C/D layout col = lane&15, row = (lane>>4)*4 + j
#pragma unroll
  for (int m = 0; m < 4; ++m) {
    const int gmBase = m0 + wr * 64 + m * 16 + g * 4;
#pragma unroll
    for (int n = 0; n < 4; ++n) {
      const int gn = n0 + wc * 64 + n * 16 + l15;
      const float bval = (EPI == 4) ? 0.0f : bias[gn];
      float vj[4];
#pragma unroll
      for (int j = 0; j < 4; ++j) vj[j] = acc[m][n][j] + bval;
      if (EPI == 0) {
        const int three = gn / 768;
        const int hh = (gn % 768) >> 6;
        const int d = gn & 63;
        const int bb = gmBase >> 11, t = gmBase & 2047;
        if (three == 2) {
          ushort4 pk;
          pk.x = f2bs(vj[0]); pk.y = f2bs(vj[1]); pk.z = f2bs(vj[2]); pk.w = f2bs(vj[3]);
          const int kt = t & 63;
          const size_t pos = ((((size_t)(bb * 12 + hh) * 32 + (t >> 6)) * 8 + (d >> 4) * 2 + (kt >> 5)) * 64
                              + ((kt >> 2) & 3) * 16 + (d & 15)) * 8 + ((kt >> 4) & 1) * 4;
          *(ushort4*)((unsigned short*)out2 + pos) = pk;
        } else if (three == 1) {
          unsigned short* dst = (unsigned short*)out1;
          const int gt = t >> 6;
          const int kt0 = t & 63;
          const int fb = d >> 5;
          const int ge = (d >> 3) & 3;
          const int e = d & 7;
          const size_t base9 = ((size_t)(bb * 12 + hh) * 32 + gt) * 8;
#pragma unroll
          for (int j = 0; j < 4; ++j) {
            const int kt = kt0 + j;
            const size_t pos = (base9 + (kt >> 4) * 2 + fb) * 512 + (ge * 16 + (kt & 15)) * 8 + e;
            dst[pos] = f2bs(vj[j]);
          }
        } else {
          unsigned short* dst = (unsigned short*)out0;
#pragma unroll
          for (int j = 0; j < 4; ++j) {
            dst[(((size_t)bb * 12 + hh) * 2048 + (t + j)) * 64 + d] = f2bs(vj[j] * 11.5415603f);
          }
        }
      } else if (EPI == 1 || EPI == 3) {
#pragma unroll
        for (int j = 0; j < 4; ++j) {
          const int gm = gmBase + j;
          ((float*)out0)[(size_t)gm * N + gn] = vj[j] + resid[(size_t)gm * N + gn];
        }
      } else if (EPI == 2) {
#pragma unroll
        for (int j = 0; j < 4; ++j) {
          const int gm = gmBase + j;
          const float vv = vj[j];
          const float u = vv * (1.0f + 0.044715f * vv * vv);
          const float E = exp2v(2.0f * 0.7978845608f * 1.4426950409f * u);
          const float ge = vv - vv / (1.0f + E);
          ((unsigned short*)out0)[(size_t)gm * N + gn] = f2bs(ge);
        }
      } else {
        unsigned short* po = (unsigned short*)out0 + (size_t)blockIdx.z * M * N;
#pragma unroll
        for (int j = 0; j < 4; ++j) {
          const int gm = gmBase + j;
          po[(size_t)gm * N + gn] = f2bs(vj[j]);
        }
      }
    }
  }
}

// ---------------- Flash attention fwd v14 ----------------
// QBLK=128: 4 waves x 32 q-rows (2 groups A/B). V-frags read once feed both
// groups' PV; K re-read per group (VGPR cap). KV-split x4 -> grid 16x24x4 =
// 1536 = 6 blocks/CU at 24KB LDS. NT=8. Inline pairwise softmax (no e array).
template<int SPLIT>
__global__ __launch_bounds__(256, 6)
void attn_fwd(const unsigned short* __restrict__ Q,
              const unsigned short* __restrict__ Kf,
              const unsigned short* __restrict__ Vf,
              unsigned short* __restrict__ O,
              unsigned short* __restrict__ Op, float* __restrict__ Mb, float* __restrict__ Lb)
{
  __shared__ __align__(1024) unsigned short Ks[4096];     // single buffer
  __shared__ __align__(1024) unsigned short Vs[2][4096];  // double buffer
  const int tid = threadIdx.x, lane = tid & 63, w = tid >> 6;
  const int l15 = lane & 15, g = lane >> 4;

  const int nwg = gridDim.x * gridDim.y;          // 384
  const int hw = blockIdx.y * gridDim.x + blockIdx.x;
  const int virt = (hw & 7) * (nwg >> 3) + (hw >> 3);
  const int qblk = virt & 15;
  const int bh = virt >> 4;
  const int b = bh / 12, h = bh % 12;
  const int q0 = qblk * 128;
  const int part = SPLIT ? blockIdx.z : 0;
  const int NT = SPLIT ? 8 : 32;
  const int T0 = part * 8;
  const unsigned short* Qb = Q  + (size_t)bh * 2048 * 64;
  const unsigned short* Kb = Kf + (size_t)bh * 2048 * 64;
  const unsigned short* Vb = Vf + (size_t)bh * 2048 * 64;

  const int qra = q0 + w * 32 + l15;
  const int qrb = qra + 16;
  short8 qfa[2], qfb[2];
  qfa[0] = *(const short8*)(Qb + (size_t)qra * 64 + g * 8);
  qfa[1] = *(const short8*)(Qb + (size_t)qra * 64 + 32 + g * 8);
  qfb[0] = *(const short8*)(Qb + (size_t)qrb * 64 + g * 8);
  qfb[1] = *(const short8*)(Qb + (size_t)qrb * 64 + 32 + g * 8);

  float m_a = -1e30f, l_a = 0.f, m_b = -1e30f, l_b = 0.f;
  f32x4 oa[4], ob[4];
#pragma unroll
  for (int dc = 0; dc < 4; ++dc) { oa[dc] = (f32x4){0.f,0.f,0.f,0.f}; ob[dc] = (f32x4){0.f,0.f,0.f,0.f}; }

  auto stageK = [&](int gt) {
#pragma unroll
    for (int i = 0; i < 2; ++i) {
      const int chunk = tid + i * 256;
      gload16(Kb + (size_t)gt * 4096 + chunk * 8, (char*)&Ks[0] + chunk * 16);
    }
  };
  auto stageV = [&](int buf, int gt) {
#pragma unroll
    for (int i = 0; i < 2; ++i) {
      const int chunk = tid + i * 256;
      gload16(Vb + (size_t)gt * 4096 + chunk * 8, (char*)&Vs[buf][0] + chunk * 16);
    }
  };

  stageK(T0);
  stageV(0, T0);

  for (int t = 0; t < NT; ++t) {
    const int vbuf = t & 1;
    asm volatile("s_waitcnt vmcnt(0)" ::: "memory");
    __builtin_amdgcn_s_barrier();                     // bar1
    asm volatile("" ::: "memory");
    if (t + 1 < NT) stageV(vbuf ^ 1, T0 + t + 1);

    // --- QK group A ---
    f32x4 s2[4];
#pragma unroll
    for (int n = 0; n < 4; ++n) s2[n] = (f32x4){0.f, 0.f, 0.f, 0.f};
    __builtin_amdgcn_s_setprio(1);
#pragma unroll
    for (int n = 0; n < 4; ++n) {
      short8 kf0 = *(const short8*)(&Ks[(n * 2 + 0) * 512 + lane * 8]);
      short8 kf1 = *(const short8*)(&Ks[(n * 2 + 1) * 512 + lane * 8]);
      s2[n] = __builtin_amdgcn_mfma_f32_16x16x32_bf16(kf0, qfa[0], s2[n], 0, 0, 0);
      s2[n] = __builtin_amdgcn_mfma_f32_16x16x32_bf16(kf1, qfa[1], s2[n], 0, 0, 0);
    }
    __builtin_amdgcn_s_setprio(0);

    // --- softmax A (inline pairwise) ---
    unsigned pwa[2][4], pwb[2][4];
    {
      float mx = max3f(max3f(s2[0][0], s2[0][1], s2[0][2]),
                       max3f(s2[0][3], s2[1][0], s2[1][1]),
                       max3f(s2[1][2], s2[1][3], s2[2][0]));
      mx = max3f(mx, max3f(s2[2][1], s2[2][2], s2[2][3]),
                     max3f(s2[3][0], s2[3][1], fmaxf(s2[3][2], s2[3][3])));
      mx = fmaxf(mx, __shfl_xor(mx, 16, 64));
      mx = fmaxf(mx, __shfl_xor(mx, 32, 64));
      if (__any(mx > m_a + 8.0f)) {
        const float mn = fmaxf(m_a, mx);
        const float alpha = exp2v(m_a - mn);
        m_a = mn;
        l_a *= alpha;
#pragma unroll
        for (int j = 0; j < 4; ++j) {
          const float aB = __shfl(alpha, (lane & 48) | (g * 4 + j), 64);
#pragma unroll
          for (int dc = 0; dc < 4; ++dc) oa[dc][j] *= aB;
        }
      }
      float rs = 0.f;
#pragma unroll
      for (int kc = 0; kc < 2; ++kc) {
        float e0, e1;
        e0 = exp2v(s2[2*kc][0] - m_a);   e1 = exp2v(s2[2*kc][1] - m_a);
        rs += e0 + e1; pwa[kc][0] = pkbf(e0, e1);
        e0 = exp2v(s2[2*kc][2] - m_a);   e1 = exp2v(s2[2*kc][3] - m_a);
        rs += e0 + e1; pwa[kc][1] = pkbf(e0, e1);
        e0 = exp2v(s2[2*kc+1][0] - m_a); e1 = exp2v(s2[2*kc+1][1] - m_a);
        rs += e0 + e1; pwa[kc][2] = pkbf(e0, e1);
        e0 = exp2v(s2[2*kc+1][2] - m_a); e1 = exp2v(s2[2*kc+1][3] - m_a);
        rs += e0 + e1; pwa[kc][3] = pkbf(e0, e1);
      }
      l_a += rs;
    }

    // --- QK group B (re-read kf) ---
#pragma unroll
    for (int n = 0; n < 4; ++n) s2[n] = (f32x4){0.f, 0.f, 0.f, 0.f};
    __builtin_amdgcn_s_setprio(1);
#pragma unroll
    for (int n = 0; n < 4; ++n) {
      short8 kf0 = *(const short8*)(&Ks[(n * 2 + 0) * 512 + lane * 8]);
      short8 kf1 = *(const short8*)(&Ks[(n * 2 + 1) * 512 + lane * 8]);
      s2[n] = __builtin_amdgcn_mfma_f32_16x16x32_bf16(kf0, qfb[0], s2[n], 0, 0, 0);
      s2[n] = __builtin_amdgcn_mfma_f32_16x16x32_bf16(kf1, qfb[1], s2[n], 0, 0, 0);
    }
    __builtin_amdgcn_s_setprio(0);

    asm volatile("" ::: "memory");
    __builtin_amdgcn_s_barrier();                     // bar2: all K reads done
    asm volatile("" ::: "memory");
    if (t + 1 < NT) stageK(T0 + t + 1);

    // --- softmax B ---
    {
      float mx = max3f(max3f(s2[0][0], s2[0][1], s2[0][2]),
                       max3f(s2[0][3], s2[1][0], s2[1][1]),
                       max3f(s2[1][2], s2[1][3], s2[2][0]));
      mx = max3f(mx, max3f(s2[2][1], s2[2][2], s2[2][3]),
                     max3f(s2[3][0], s2[3][1], fmaxf(s2[3][2], s2[3][3])));
      mx = fmaxf(mx, __shfl_xor(mx, 16, 64));
      mx = fmaxf(mx, __shfl_xor(mx, 32, 64));
      if (__any(mx > m_b + 8.0f)) {
        const float mn = fmaxf(m_b, mx);
        const float alpha = exp2v(m_b - mn);
        m_b = mn;
        l_b *= alpha;
#pragma unroll
        for (int j = 0; j < 4; ++j) {
          const float aB = __shfl(alpha, (lane & 48) | (g * 4 + j), 64);
#pragma unroll
          for (int dc = 0; dc < 4; ++dc) ob[dc][j] *= aB;
        }
      }
      float rs = 0.f;
#pragma unroll
      for (int kc = 0; kc < 2; ++kc) {
        float e0, e1;
        e0 = exp2v(s2[2*kc][0] - m_b);   e1 = exp2v(s2[2*kc][1] - m_b);
        rs += e0 + e1; pwb[kc][0] = pkbf(e0, e1);
        e0 = exp2v(s2[2*kc][2] - m_b);   e1 = exp2v(s2[2*kc][3] - m_b);
        rs += e0 + e1; pwb[kc][1] = pkbf(e0, e1);
        e0 = exp2v(s2[2*kc+1][0] - m_b); e1 = exp2v(s2[2*kc+1][1] - m_b);
        rs += e0 + e1; pwb[kc][2] = pkbf(e0, e1);
        e0 = exp2v(s2[2*kc+1][2] - m_b); e1 = exp2v(s2[2*kc+1][3] - m_b);
        rs += e0 + e1; pwb[kc][3] = pkbf(e0, e1);
      }
      l_b += rs;
    }

    // --- PV: each V-frag read feeds BOTH groups ---
    const char* vsb = (const char*)&Vs[vbuf][0];
    __builtin_amdgcn_s_setprio(1);
#pragma unroll
    for (int kc = 0; kc < 2; ++kc) {
      i32x4 pta; pta.x = (int)pwa[kc][0]; pta.y = (int)pwa[kc][1]; pta.z = (int)pwa[kc][2]; pta.w = (int)pwa[kc][3];
      i32x4 ptb; ptb.x = (int)pwb[kc][0]; ptb.y = (int)pwb[kc][1]; ptb.z = (int)pwb[kc][2]; ptb.w = (int)pwb[kc][3];
      short8 pfa = *(short8*)&pta;
      short8 pfb = *(short8*)&ptb;
#pragma unroll
      for (int dc = 0; dc < 4; ++dc) {
        short8 vfr = *(const short8*)(vsb + (((dc * 2 + kc) * 64 + lane) * 16));
        oa[dc] = __builtin_amdgcn_mfma_f32_16x16x32_bf16(pfa, vfr, oa[dc], 0, 0, 0);
        ob[dc] = __builtin_amdgcn_mfma_f32_16x16x32_bf16(pfb, vfr, ob[dc], 0, 0, 0);
      }
    }
    __builtin_amdgcn_s_setprio(0);
    asm volatile("" ::: "memory");
  }

  // --- epilogue ---
  l_a += __shfl_xor(l_a, 16, 64);
  l_a += __shfl_xor(l_a, 32, 64);
  l_b += __shfl_xor(l_b, 16, 64);
  l_b += __shfl_xor(l_b, 32, 64);
  if (SPLIT) {
    const int rowBase = (part * 24 + bh) * 2048;
    if (g == 0) {
      Mb[rowBase + qra] = m_a;
      Lb[rowBase + qra] = l_a;
      Mb[rowBase + qrb] = m_b;
      Lb[rowBase + qrb] = l_b;
    }
#pragma unroll
    for (int j = 0; j < 4; ++j) {
      const int rowA = q0 + w * 32 + g * 4 + j;
#pragma unroll
      for (int dc = 0; dc < 4; ++dc) {
        Op[(size_t)(rowBase + rowA) * 64 + dc * 16 + l15] = f2bs(oa[dc][j]);
        Op[(size_t)(rowBase + rowA + 16) * 64 + dc * 16 + l15] = f2bs(ob[dc][j]);
      }
    }
  } else {
#pragma unroll
    for (int j = 0; j < 4; ++j) {
      const int src = (lane & 48) | (g * 4 + j);
      const float invA = 1.0f / __shfl(l_a, src, 64);
      const float invB = 1.0f / __shfl(l_b, src, 64);
      const int rowA = q0 + w * 32 + g * 4 + j;
#pragma unroll
      for (int dc = 0; dc < 4; ++dc) {
        O[((size_t)b * 2048 + rowA) * 768 + h * 64 + dc * 16 + l15] = f2bs(oa[dc][j] * invA);
        O[((size_t)b * 2048 + rowA + 16) * 768 + h * 64 + dc * 16 + l15] = f2bs(ob[dc][j] * invB);
      }
    }
  }
}

// ---------------- flash combine: merge 4 KV-quarters (bf16 partials) ----------------
__global__ __launch_bounds__(256)
void attn_combine(const unsigned short* __restrict__ Op, const float* __restrict__ Mb,
                  const float* __restrict__ Lb, unsigned short* __restrict__ O)
{
  const int idx = blockIdx.x * 256 + threadIdx.x;
  const int e4 = idx * 4;
  const int row = e4 >> 6;          // bh*2048 + q, 0..49151
  const int d0 = e4 & 63;
  float m0 = Mb[row], m1 = Mb[49152 + row], m2 = Mb[2*49152 + row], m3 = Mb[3*49152 + row];
  const float mm = fmaxf(fmaxf(m0, m1), fmaxf(m2, m3));
  const float w0 = exp2v(m0 - mm), w1 = exp2v(m1 - mm), w2 = exp2v(m2 - mm), w3 = exp2v(m3 - mm);
  const float inv = 1.0f / (Lb[row] * w0 + Lb[49152 + row] * w1 +
                            Lb[2*49152 + row] * w2 + Lb[3*49152 + row] * w3);
  ushort4 a0 = *(const ushort4*)(Op + (size_t)row * 64 + d0);
  ushort4 a1 = *(const ushort4*)(Op + 49152ull * 64 + (size_t)row * 64 + d0);
  ushort4 a2 = *(const ushort4*)(Op + 2ull * 49152 * 64 + (size_t)row * 64 + d0);
  ushort4 a3 = *(const ushort4*)(Op + 3ull * 49152 * 64 + (size_t)row * 64 + d0);
  ushort4 r;
  r.x = f2bs((bs2f(a0.x)*w0 + bs2f(a1.x)*w1 + bs2f(a2.x)*w2 + bs2f(a3.x)*w3) * inv);
  r.y = f2bs((bs2f(a0.y)*w0 + bs2f(a1.y)*w1 + bs2f(a2.y)*w2 + bs2f(a3.y)*w3) * inv);
  r.z = f2bs((bs2f(a0.z)*w0 + bs2f(a1.z)*w1 + bs2f(a2.z)*w2 + bs2f(a3.z)*w3) * inv);
  r.w = f2bs((bs2f(a0.w)*w0 + bs2f(a1.w)*w1 + bs2f(a2.w)*w2 + bs2f(a3.w)*w3) * inv);
  const int bh = row >> 11, q = row & 2047;
  const int b = bh / 12, hh = bh % 12;
  *(ushort4*)(O + ((size_t)(b * 2048 + q)) * 768 + hh * 64 + d0) = r;
}

extern "C" void kernel_launch(void* const* d_in, const int* in_sizes, int n_in,
                              void* d_out, int out_size, void* d_ws, size_t ws_size,
                              hipStream_t stream)
{
  const float* x      = (const float*)d_in[0];
  const float* ln1_w  = (const float*)d_in[1];
  const float* ln1_b  = (const float*)d_in[2];
  const float* qkv_w  = (const float*)d_in[3];
  const float* qkv_b  = (const float*)d_in[4];
  const float* proj_w = (const float*)d_in[5];
  const float* proj_b = (const float*)d_in[6];
  const float* ln2_w  = (const float*)d_in[7];
  const float* ln2_b  = (const float*)d_in[8];
  const float* fc1_w  = (const float*)d_in[9];
  const float* fc1_b  = (const float*)d_in[10];
  const float* fc2_w  = (const float*)d_in[11];
  const float* fc2_b  = (const float*)d_in[12];

  char* base = (char*)d_ws;
  size_t off = 0;
  auto take = [&](size_t bytes) {
    void* r = base + off;
    off = (off + bytes + 255) & ~(size_t)255;
    return r;
  };
  unsigned short* wq = (unsigned short*)take(2304ull * 768 * 2);
  unsigned short* wp = (unsigned short*)take(768ull * 768 * 2);
  unsigned short* w1 = (unsigned short*)take(3072ull * 768 * 2);
  unsigned short* w2 = (unsigned short*)take(768ull * 3072 * 2);
  unsigned short* h  = (unsigned short*)take(4096ull * 768 * 2);
  float* x2          = (float*)take(4096ull * 768 * 4);
  char* big          = (char*)take(4096ull * 3072 * 2);
  unsigned short* Qb = (unsigned short*)big;
  unsigned short* Kb = (unsigned short*)(big + 4096ull * 768 * 2);      // frag-major
  unsigned short* Vb = (unsigned short*)(big + 2ull * 4096 * 768 * 2);  // frag-major
  unsigned short* a2 = (unsigned short*)big;
  unsigned short* part = (unsigned short*)take(4ull * 4096 * 768 * 2);  // bf16 partials
  float* Mb_         = (float*)take(4ull * 49152 * 4);
  float* Lb_         = (float*)take(4ull * 49152 * 4);
  const bool can_split = off <= ws_size;

  prep<<<11008, 256, 0, stream>>>(qkv_w, proj_w, fc1_w, fc2_w, wq, wp, w1, w2,
                                  x, ln1_w, ln1_b, h);
  gemm_nt<0><<<dim3(18, 32), 256, 0, stream>>>(h, wq, qkv_b, nullptr, Qb, Kb, Vb, 4096, 2304, 768, 768);

  if (can_split) {
    attn_fwd<1><<<dim3(16, 24, 4), 256, 0, stream>>>(Qb, Kb, Vb, nullptr, part, Mb_, Lb_);
    attn_combine<<<3072, 256, 0, stream>>>(part, Mb_, Lb_, h);
  } else {
    attn_fwd<0><<<dim3(16, 24), 256, 0, stream>>>(Qb, Kb, Vb, h, nullptr, nullptr, nullptr);
  }

  if (can_split) {
    gemm_nt<4><<<dim3(6, 32, 2), 256, 0, stream>>>(h, wp, nullptr, nullptr, part, nullptr, nullptr, 4096, 768, 384, 768);
    reduce_ln2<<<4096, 256, 0, stream>>>(part, proj_b, x, ln2_w, ln2_b, x2, h);
  } else {
    gemm_nt<1><<<dim3(6, 32), 256, 0, stream>>>(h, wp, proj_b, x, x2, nullptr, nullptr, 4096, 768, 768, 768);
    ln_kernel<<<4096, 256, 0, stream>>>(x2, ln2_w, ln2_b, h);
  }

  gemm_nt<2><<<dim3(24, 32), 256, 0, stream>>>(h, w1, fc1_b, nullptr, a2, nullptr, nullptr, 4096, 3072, 768, 768);

  if (can_split) {
    gemm_nt<4><<<dim3(6, 32, 4), 256, 0, stream>>>(a2, w2, nullptr, nullptr, part, nullptr, nullptr, 4096, 768, 768, 3072);
    reduce_k<4><<<3072, 256, 0, stream>>>(part, fc2_b, x2, (float*)d_out);
  } else {
    gemm_nt<3><<<dim3(6, 32), 256, 0, stream>>>(a2, w2, fc2_b, x2, d_out, nullptr, nullptr, 4096, 768, 3072, 3072);
  }
}

// Round 17
// 186.458 us; speedup vs baseline: 1.2974x; 1.2974x over previous
//
#include <hip/hip_runtime.h>
#include <hip/hip_bf16.h>

typedef __attribute__((ext_vector_type(8))) short short8;
typedef __attribute__((ext_vector_type(4))) float f32x4;
typedef __attribute__((ext_vector_type(4))) int i32x4;

__device__ inline unsigned short f2bs(float f) {
  union { float f; unsigned u; } v; v.f = f;
  unsigned r = v.u + 0x7fff + ((v.u >> 16) & 1);
  return (unsigned short)(r >> 16);
}

__device__ inline float bs2f(unsigned short u) {
  union { unsigned u; float f; } c; c.u = (unsigned)u << 16; return c.f;
}

__device__ inline unsigned pkbf(float a, float b) {
  __hip_bfloat162 h = __float22bfloat162_rn(float2{a, b});
  union { __hip_bfloat162 h; unsigned u; } c; c.h = h;
  return c.u;
}

__device__ inline float exp2v(float x) {
  float r; asm("v_exp_f32 %0, %1" : "=v"(r) : "v"(x)); return r;
}

__device__ inline float max3f(float a, float b, float c) {
  return fmaxf(fmaxf(a, b), c);
}

__device__ inline void gload16(const void* g, void* l) {
  __builtin_amdgcn_global_load_lds((const __attribute__((address_space(1))) void*)g,
                                   (__attribute__((address_space(3))) void*)l,
                                   16, 0, 0);
}

// ---------------- prep: weight cvt (blocks 0..6911) + LN1 (blocks 6912..11007) ----------------
__global__ __launch_bounds__(256)
void prep(const float* __restrict__ s0, const float* __restrict__ s1,
          const float* __restrict__ s2, const float* __restrict__ s3,
          unsigned short* __restrict__ d0, unsigned short* __restrict__ d1,
          unsigned short* __restrict__ d2, unsigned short* __restrict__ d3,
          const float* __restrict__ x, const float* __restrict__ lw,
          const float* __restrict__ lb, unsigned short* __restrict__ out)
{
  if (blockIdx.x < 6912) {
    size_t i = (size_t)blockIdx.x * 256 + threadIdx.x;
    const float* src; unsigned short* dst;
    if (i < 442368) { src = s0; dst = d0; }
    else if (i < 589824) { src = s1; dst = d1; i -= 442368; }
    else if (i < 1179648) { src = s2; dst = d2; i -= 589824; }
    else { src = s3; dst = d3; i -= 1179648; }
    float4 v = ((const float4*)src)[i];
    ushort4 o;
    o.x = f2bs(v.x); o.y = f2bs(v.y); o.z = f2bs(v.z); o.w = f2bs(v.w);
    ((ushort4*)dst)[i] = o;
    return;
  }
  const int row = blockIdx.x - 6912;
  const float* xr = x + (size_t)row * 768;
  float v[3];
  float s = 0.f, sq = 0.f;
#pragma unroll
  for (int i = 0; i < 3; ++i) {
    v[i] = xr[threadIdx.x + i * 256];
    s += v[i]; sq += v[i] * v[i];
  }
#pragma unroll
  for (int d = 1; d < 64; d <<= 1) {
    s  += __shfl_xor(s, d, 64);
    sq += __shfl_xor(sq, d, 64);
  }
  __shared__ float ss[4], ssq[4];
  const int wv = threadIdx.x >> 6;
  if ((threadIdx.x & 63) == 0) { ss[wv] = s; ssq[wv] = sq; }
  __syncthreads();
  s  = ss[0] + ss[1] + ss[2] + ss[3];
  sq = ssq[0] + ssq[1] + ssq[2] + ssq[3];
  const float mu = s * (1.0f / 768.0f);
  const float var = sq * (1.0f / 768.0f) - mu * mu;
  const float rstd = rsqrtf(var + 1e-5f);
#pragma unroll
  for (int i = 0; i < 3; ++i) {
    const int c = threadIdx.x + i * 256;
    out[(size_t)row * 768 + c] = f2bs((v[i] - mu) * rstd * lw[c] + lb[c]);
  }
}

// ---------------- LayerNorm (fallback path only) ----------------
__global__ __launch_bounds__(256)
void ln_kernel(const float* __restrict__ x, const float* __restrict__ w,
               const float* __restrict__ bsh, unsigned short* __restrict__ out)
{
  const int row = blockIdx.x;
  const float* xr = x + (size_t)row * 768;
  float v[3];
  float s = 0.f, sq = 0.f;
#pragma unroll
  for (int i = 0; i < 3; ++i) {
    v[i] = xr[threadIdx.x + i * 256];
    s += v[i]; sq += v[i] * v[i];
  }
#pragma unroll
  for (int d = 1; d < 64; d <<= 1) {
    s  += __shfl_xor(s, d, 64);
    sq += __shfl_xor(sq, d, 64);
  }
  __shared__ float ss[4], ssq[4];
  const int wv = threadIdx.x >> 6;
  if ((threadIdx.x & 63) == 0) { ss[wv] = s; ssq[wv] = sq; }
  __syncthreads();
  s  = ss[0] + ss[1] + ss[2] + ss[3];
  sq = ssq[0] + ssq[1] + ssq[2] + ssq[3];
  const float mu = s * (1.0f / 768.0f);
  const float var = sq * (1.0f / 768.0f) - mu * mu;
  const float rstd = rsqrtf(var + 1e-5f);
#pragma unroll
  for (int i = 0; i < 3; ++i) {
    const int c = threadIdx.x + i * 256;
    out[(size_t)row * 768 + c] = f2bs((v[i] - mu) * rstd * w[c] + bsh[c]);
  }
}

// ---------------- proj reduce (bf16 partials) + residual + LN2 fused ----------------
__global__ __launch_bounds__(256)
void reduce_ln2(const unsigned short* __restrict__ p, const float* __restrict__ bias,
                const float* __restrict__ resid, const float* __restrict__ lw,
                const float* __restrict__ lb, float* __restrict__ x2,
                unsigned short* __restrict__ h)
{
  const size_t MN = 4096ull * 768;
  const int row = blockIdx.x;
  const size_t r0 = (size_t)row * 768;
  float v[3];
  float s = 0.f, sq = 0.f;
#pragma unroll
  for (int i = 0; i < 3; ++i) {
    const int c = threadIdx.x + i * 256;
    const float a = bs2f(p[r0 + c]) + bs2f(p[MN + r0 + c]) + bias[c] + resid[r0 + c];
    x2[r0 + c] = a;
    v[i] = a; s += a; sq += a * a;
  }
#pragma unroll
  for (int d = 1; d < 64; d <<= 1) {
    s  += __shfl_xor(s, d, 64);
    sq += __shfl_xor(sq, d, 64);
  }
  __shared__ float ss[4], ssq[4];
  const int wv = threadIdx.x >> 6;
  if ((threadIdx.x & 63) == 0) { ss[wv] = s; ssq[wv] = sq; }
  __syncthreads();
  s  = ss[0] + ss[1] + ss[2] + ss[3];
  sq = ssq[0] + ssq[1] + ssq[2] + ssq[3];
  const float mu = s * (1.0f / 768.0f);
  const float var = sq * (1.0f / 768.0f) - mu * mu;
  const float rstd = rsqrtf(var + 1e-5f);
#pragma unroll
  for (int i = 0; i < 3; ++i) {
    const int c = threadIdx.x + i * 256;
    h[r0 + c] = f2bs((v[i] - mu) * rstd * lw[c] + lb[c]);
  }
}

// ---------------- split-K reduce (bf16 partials) ----------------
template<int S>
__global__ __launch_bounds__(256)
void reduce_k(const unsigned short* __restrict__ p, const float* __restrict__ bias,
              const float* __restrict__ resid, float* __restrict__ out)
{
  const size_t MN = 4096ull * 768;
  const size_t i = ((size_t)blockIdx.x * 256 + threadIdx.x) * 4;
  float ax = 0.f, ay = 0.f, az = 0.f, aw = 0.f;
#pragma unroll
  for (int s = 0; s < S; ++s) {
    ushort4 b = *(const ushort4*)(p + s * MN + i);
    ax += bs2f(b.x); ay += bs2f(b.y); az += bs2f(b.z); aw += bs2f(b.w);
  }
  const int col = (int)(i % 768);
  float4 bb = *(const float4*)(bias + col);
  float4 rr = *(const float4*)(resid + i);
  float4 r;
  r.x = ax + bb.x + rr.x; r.y = ay + bb.y + rr.y;
  r.z = az + bb.z + rr.z; r.w = aw + bb.w + rr.w;
  *(float4*)(out + i) = r;
}

// ---------------- NT GEMM (r13 chunk-swizzled staging) ----------------
template<int EPI>
__global__ __launch_bounds__(256, 3)
void gemm_nt(const unsigned short* __restrict__ A,
             const unsigned short* __restrict__ Bw,
             const float* __restrict__ bias,
             const float* __restrict__ resid,
             void* __restrict__ out0, void* __restrict__ out1, void* __restrict__ out2,
             int M, int N, int Kslice, int Kstride)
{
  __shared__ __align__(16) unsigned short As[3][128 * 32];
  __shared__ __align__(16) unsigned short Bs[3][128 * 32];
  const int tid = threadIdx.x;
  const int lane = tid & 63;
  const int w = tid >> 6;
  const int wr = w >> 1, wc = w & 1;
  const int l15 = lane & 15, g = lane >> 4;

  const int nwg = gridDim.x * gridDim.y;
  const int hw = blockIdx.y * gridDim.x + blockIdx.x;
  const int virt = (hw & 7) * (nwg >> 3) + (hw >> 3);
  const int m0 = (virt / gridDim.x) * 128;
  const int n0 = (virt % gridDim.x) * 128;
  const int kbase = blockIdx.z * Kslice;

  f32x4 acc[4][4];
#pragma unroll
  for (int m = 0; m < 4; ++m)
#pragma unroll
    for (int n = 0; n < 4; ++n)
      acc[m][n] = (f32x4){0.f, 0.f, 0.f, 0.f};

  auto stage = [&](int buf, int k0) {
#pragma unroll
    for (int i = 0; i < 2; ++i) {
      const int f = tid + i * 256;
      const int row = f >> 2, c8 = f & 3;
      const int sc = c8 ^ (row & 3);
      gload16(A  + (size_t)(m0 + row) * Kstride + kbase + k0 + sc * 8, (char*)&As[buf][0] + f * 16);
      gload16(Bw + (size_t)(n0 + row) * Kstride + kbase + k0 + sc * 8, (char*)&Bs[buf][0] + f * 16);
    }
  };

  const int NT = Kslice >> 5;
  stage(0, 0);
  stage(1, 32);

  for (int t = 0; t < NT; ++t) {
    const int buf = t % 3;
    if (t + 1 < NT) {
      asm volatile("s_waitcnt vmcnt(4)" ::: "memory");
    } else {
      asm volatile("s_waitcnt vmcnt(0)" ::: "memory");
    }
    __builtin_amdgcn_s_barrier();
    asm volatile("" ::: "memory");
    if (t + 2 < NT) stage((t + 2) % 3, (t + 2) * 32);

    short8 af[4], bfr[4];
#pragma unroll
    for (int m = 0; m < 4; ++m) {
      const int r = wr * 64 + m * 16 + l15;
      af[m] = *(const short8*)((const char*)&As[buf][0] + ((size_t)r * 32 + (g ^ (r & 3)) * 8) * 2);
    }
#pragma unroll
    for (int n = 0; n < 4; ++n) {
      const int r = wc * 64 + n * 16 + l15;
      bfr[n] = *(const short8*)((const char*)&Bs[buf][0] + ((size_t)r * 32 + (g ^ (r & 3)) * 8) * 2);
    }
#pragma unroll
    for (int m = 0; m < 4; ++m)
#pragma unroll
      for (int n = 0; n < 4; ++n)
        acc[m][n] = __builtin_amdgcn_mfma_f32_16x16x32_bf16(af[m], bfr[n], acc[m][n], 0, 0, 0);
    asm volatile("" ::: "memory");
  }

  // epilogue: C/D layout col = lane&15, row = (lane>>4)*4 + j
#pragma unroll
  for (int m = 0; m < 4; ++m) {
    const int gmBase = m0 + wr * 64 + m * 16 + g * 4;
#pragma unroll
    for (int n = 0; n < 4; ++n) {
      const int gn = n0 + wc * 64 + n * 16 + l15;
      const float bval = (EPI == 4) ? 0.0f : bias[gn];
      float vj[4];
#pragma unroll
      for (int j = 0; j < 4; ++j) vj[j] = acc[m][n][j] + bval;
      if (EPI == 0) {
        const int three = gn / 768;
        const int hh = (gn % 768) >> 6;
        const int d = gn & 63;
        const int bb = gmBase >> 11, t = gmBase & 2047;
        if (three == 2) {
          ushort4 pk;
          pk.x = f2bs(vj[0]); pk.y = f2bs(vj[1]); pk.z = f2bs(vj[2]); pk.w = f2bs(vj[3]);
          const int kt = t & 63;
          const size_t pos = ((((size_t)(bb * 12 + hh) * 32 + (t >> 6)) * 8 + (d >> 4) * 2 + (kt >> 5)) * 64
                              + ((kt >> 2) & 3) * 16 + (d & 15)) * 8 + ((kt >> 4) & 1) * 4;
          *(ushort4*)((unsigned short*)out2 + pos) = pk;
        } else if (three == 1) {
          unsigned short* dst = (unsigned short*)out1;
          const int gt = t >> 6;
          const int kt0 = t & 63;
          const int fb = d >> 5;
          const int ge = (d >> 3) & 3;
          const int e = d & 7;
          const size_t base9 = ((size_t)(bb * 12 + hh) * 32 + gt) * 8;
#pragma unroll
          for (int j = 0; j < 4; ++j) {
            const int kt = kt0 + j;
            const size_t pos = (base9 + (kt >> 4) * 2 + fb) * 512 + (ge * 16 + (kt & 15)) * 8 + e;
            dst[pos] = f2bs(vj[j]);
          }
        } else {
          unsigned short* dst = (unsigned short*)out0;
#pragma unroll
          for (int j = 0; j < 4; ++j) {
            dst[(((size_t)bb * 12 + hh) * 2048 + (t + j)) * 64 + d] = f2bs(vj[j] * 11.5415603f);
          }
        }
      } else if (EPI == 1 || EPI == 3) {
#pragma unroll
        for (int j = 0; j < 4; ++j) {
          const int gm = gmBase + j;
          ((float*)out0)[(size_t)gm * N + gn] = vj[j] + resid[(size_t)gm * N + gn];
        }
      } else if (EPI == 2) {
#pragma unroll
        for (int j = 0; j < 4; ++j) {
          const int gm = gmBase + j;
          const float vv = vj[j];
          const float u = vv * (1.0f + 0.044715f * vv * vv);
          const float E = exp2v(2.0f * 0.7978845608f * 1.4426950409f * u);
          const float ge = vv - vv / (1.0f + E);
          ((unsigned short*)out0)[(size_t)gm * N + gn] = f2bs(ge);
        }
      } else {
        unsigned short* po = (unsigned short*)out0 + (size_t)blockIdx.z * M * N;
#pragma unroll
        for (int j = 0; j < 4; ++j) {
          const int gm = gmBase + j;
          po[(size_t)gm * N + gn] = f2bs(vj[j]);
        }
      }
    }
  }
}

// ---------------- Flash attention fwd v13 (r15 verbatim) ----------------
// KV-split x2, 24KB LDS (K single-buf + V double-buf), 6 blocks/CU, two
// barriers/tile; K and V frag-major in global -> all staging lane-linear.
template<int SPLIT>
__global__ __launch_bounds__(256, 6)
void attn_fwd(const unsigned short* __restrict__ Q,
              const unsigned short* __restrict__ Kf,
              const unsigned short* __restrict__ Vf,
              unsigned short* __restrict__ O,
              unsigned short* __restrict__ Op, float* __restrict__ Mb, float* __restrict__ Lb)
{
  __shared__ __align__(1024) unsigned short Ks[4096];
  __shared__ __align__(1024) unsigned short Vs[2][4096];
  const int tid = threadIdx.x, lane = tid & 63, w = tid >> 6;
  const int l15 = lane & 15, g = lane >> 4;

  const int hw = blockIdx.y * gridDim.x + blockIdx.x;
  const int virt = (hw & 7) * 96 + (hw >> 3);
  const int qblk = virt & 31;
  const int bh = virt >> 5;
  const int b = bh / 12, h = bh % 12;
  const int q0 = qblk * 64;
  const int half = SPLIT ? blockIdx.z : 0;
  const int NT = SPLIT ? 16 : 32;
  const int T0 = half * 16;
  const unsigned short* Qb = Q  + (size_t)bh * 2048 * 64;
  const unsigned short* Kb = Kf + (size_t)bh * 2048 * 64;
  const unsigned short* Vb = Vf + (size_t)bh * 2048 * 64;

  const int qr = q0 + w * 16 + l15;
  short8 qf[2];
  qf[0] = *(const short8*)(Qb + (size_t)qr * 64 + g * 8);
  qf[1] = *(const short8*)(Qb + (size_t)qr * 64 + 32 + g * 8);

  float m_run = -1e30f, l_part = 0.f;
  f32x4 o_acc[4];
#pragma unroll
  for (int dc = 0; dc < 4; ++dc) o_acc[dc] = (f32x4){0.f, 0.f, 0.f, 0.f};

  auto stageK = [&](int gt) {
#pragma unroll
    for (int i = 0; i < 2; ++i) {
      const int chunk = tid + i * 256;
      gload16(Kb + (size_t)gt * 4096 + chunk * 8, (char*)&Ks[0] + chunk * 16);
    }
  };
  auto stageV = [&](int buf, int gt) {
#pragma unroll
    for (int i = 0; i < 2; ++i) {
      const int chunk = tid + i * 256;
      gload16(Vb + (size_t)gt * 4096 + chunk * 8, (char*)&Vs[buf][0] + chunk * 16);
    }
  };

  stageK(T0);
  stageV(0, T0);

  for (int t = 0; t < NT; ++t) {
    const int vbuf = t & 1;
    asm volatile("s_waitcnt vmcnt(0)" ::: "memory");
    __builtin_amdgcn_s_barrier();                     // bar1: V[t-1] readers done
    asm volatile("" ::: "memory");
    if (t + 1 < NT) stageV(vbuf ^ 1, T0 + t + 1);

    f32x4 s2[4];
#pragma unroll
    for (int n = 0; n < 4; ++n) s2[n] = (f32x4){0.f, 0.f, 0.f, 0.f};
    __builtin_amdgcn_s_setprio(1);
#pragma unroll
    for (int n = 0; n < 4; ++n) {
      short8 kf0 = *(const short8*)(&Ks[(n * 2 + 0) * 512 + lane * 8]);
      short8 kf1 = *(const short8*)(&Ks[(n * 2 + 1) * 512 + lane * 8]);
      s2[n] = __builtin_amdgcn_mfma_f32_16x16x32_bf16(kf0, qf[0], s2[n], 0, 0, 0);
      s2[n] = __builtin_amdgcn_mfma_f32_16x16x32_bf16(kf1, qf[1], s2[n], 0, 0, 0);
    }
    __builtin_amdgcn_s_setprio(0);

    asm volatile("" ::: "memory");
    __builtin_amdgcn_s_barrier();                     // bar2: K reads done
    asm volatile("" ::: "memory");
    if (t + 1 < NT) stageK(T0 + t + 1);

    float mx = max3f(max3f(s2[0][0], s2[0][1], s2[0][2]),
                     max3f(s2[0][3], s2[1][0], s2[1][1]),
                     max3f(s2[1][2], s2[1][3], s2[2][0]));
    mx = max3f(mx, max3f(s2[2][1], s2[2][2], s2[2][3]),
                   max3f(s2[3][0], s2[3][1], fmaxf(s2[3][2], s2[3][3])));
    mx = fmaxf(mx, __shfl_xor(mx, 16, 64));
    mx = fmaxf(mx, __shfl_xor(mx, 32, 64));
    if (__any(mx > m_run + 8.0f)) {
      const float mn = fmaxf(m_run, mx);
      const float alpha = exp2v(m_run - mn);
      m_run = mn;
      l_part *= alpha;
#pragma unroll
      for (int j = 0; j < 4; ++j) {
        const float aB = __shfl(alpha, (lane & 48) | (g * 4 + j), 64);
#pragma unroll
        for (int dc = 0; dc < 4; ++dc) o_acc[dc][j] *= aB;
      }
    }
    float e[4][4];
    float rs = 0.f;
#pragma unroll
    for (int n = 0; n < 4; ++n)
#pragma unroll
      for (int j = 0; j < 4; ++j) {
        e[n][j] = exp2v(s2[n][j] - m_run);
        rs += e[n][j];
      }
    l_part += rs;

    unsigned pw[2][4];
#pragma unroll
    for (int kc = 0; kc < 2; ++kc) {
      pw[kc][0] = pkbf(e[2 * kc][0],     e[2 * kc][1]);
      pw[kc][1] = pkbf(e[2 * kc][2],     e[2 * kc][3]);
      pw[kc][2] = pkbf(e[2 * kc + 1][0], e[2 * kc + 1][1]);
      pw[kc][3] = pkbf(e[2 * kc + 1][2], e[2 * kc + 1][3]);
    }

    const char* vsb = (const char*)&Vs[vbuf][0];
    __builtin_amdgcn_s_setprio(1);
#pragma unroll
    for (int kc = 0; kc < 2; ++kc) {
      i32x4 pt; pt.x = (int)pw[kc][0]; pt.y = (int)pw[kc][1]; pt.z = (int)pw[kc][2]; pt.w = (int)pw[kc][3];
      short8 pf = *(short8*)&pt;
#pragma unroll
      for (int dc = 0; dc < 4; ++dc) {
        short8 vfr = *(const short8*)(vsb + (((dc * 2 + kc) * 64 + lane) * 16));
        o_acc[dc] = __builtin_amdgcn_mfma_f32_16x16x32_bf16(pf, vfr, o_acc[dc], 0, 0, 0);
      }
    }
    __builtin_amdgcn_s_setprio(0);
    asm volatile("" ::: "memory");
  }

  l_part += __shfl_xor(l_part, 16, 64);
  l_part += __shfl_xor(l_part, 32, 64);
  if (SPLIT) {
    const int rowBase = (half * 24 + bh) * 2048;
    if (g == 0) {
      const int qm = q0 + w * 16 + l15;
      Mb[rowBase + qm] = m_run;
      Lb[rowBase + qm] = l_part;
    }
#pragma unroll
    for (int j = 0; j < 4; ++j) {
      const int row = q0 + w * 16 + g * 4 + j;
#pragma unroll
      for (int dc = 0; dc < 4; ++dc)
        Op[(size_t)(rowBase + row) * 64 + dc * 16 + l15] = f2bs(o_acc[dc][j]);
    }
  } else {
#pragma unroll
    for (int j = 0; j < 4; ++j) {
      const float lB = __shfl(l_part, (lane & 48) | (g * 4 + j), 64);
      const float inv = 1.0f / lB;
      const int qrow = q0 + w * 16 + g * 4 + j;
#pragma unroll
      for (int dc = 0; dc < 4; ++dc)
        O[((size_t)b * 2048 + qrow) * 768 + h * 64 + dc * 16 + l15] = f2bs(o_acc[dc][j] * inv);
    }
  }
}

// ---------------- flash combine: merge 2 KV-halves (bf16 partials) ----------------
__global__ __launch_bounds__(256)
void attn_combine(const unsigned short* __restrict__ Op, const float* __restrict__ Mb,
                  const float* __restrict__ Lb, unsigned short* __restrict__ O)
{
  const int idx = blockIdx.x * 256 + threadIdx.x;
  const int e4 = idx * 4;
  const int row = e4 >> 6;
  const int d0 = e4 & 63;
  const float m1 = Mb[row], m2 = Mb[49152 + row];
  const float l1 = Lb[row], l2 = Lb[49152 + row];
  const float mm = fmaxf(m1, m2);
  const float w1 = exp2v(m1 - mm), w2 = exp2v(m2 - mm);
  const float inv = 1.0f / (l1 * w1 + l2 * w2);
  ushort4 a1 = *(const ushort4*)(Op + (size_t)row * 64 + d0);
  ushort4 a2 = *(const ushort4*)(Op + 49152ull * 64 + (size_t)row * 64 + d0);
  ushort4 r;
  r.x = f2bs((bs2f(a1.x) * w1 + bs2f(a2.x) * w2) * inv);
  r.y = f2bs((bs2f(a1.y) * w1 + bs2f(a2.y) * w2) * inv);
  r.z = f2bs((bs2f(a1.z) * w1 + bs2f(a2.z) * w2) * inv);
  r.w = f2bs((bs2f(a1.w) * w1 + bs2f(a2.w) * w2) * inv);
  const int bh = row >> 11, q = row & 2047;
  const int b = bh / 12, hh = bh % 12;
  *(ushort4*)(O + ((size_t)(b * 2048 + q)) * 768 + hh * 64 + d0) = r;
}

extern "C" void kernel_launch(void* const* d_in, const int* in_sizes, int n_in,
                              void* d_out, int out_size, void* d_ws, size_t ws_size,
                              hipStream_t stream)
{
  const float* x      = (const float*)d_in[0];
  const float* ln1_w  = (const float*)d_in[1];
  const float* ln1_b  = (const float*)d_in[2];
  const float* qkv_w  = (const float*)d_in[3];
  const float* qkv_b  = (const float*)d_in[4];
  const float* proj_w = (const float*)d_in[5];
  const float* proj_b = (const float*)d_in[6];
  const float* ln2_w  = (const float*)d_in[7];
  const float* ln2_b  = (const float*)d_in[8];
  const float* fc1_w  = (const float*)d_in[9];
  const float* fc1_b  = (const float*)d_in[10];
  const float* fc2_w  = (const float*)d_in[11];
  const float* fc2_b  = (const float*)d_in[12];

  char* base = (char*)d_ws;
  size_t off = 0;
  auto take = [&](size_t bytes) {
    void* r = base + off;
    off = (off + bytes + 255) & ~(size_t)255;
    return r;
  };
  unsigned short* wq = (unsigned short*)take(2304ull * 768 * 2);
  unsigned short* wp = (unsigned short*)take(768ull * 768 * 2);
  unsigned short* w1 = (unsigned short*)take(3072ull * 768 * 2);
  unsigned short* w2 = (unsigned short*)take(768ull * 3072 * 2);
  unsigned short* h  = (unsigned short*)take(4096ull * 768 * 2);
  float* x2          = (float*)take(4096ull * 768 * 4);
  char* big          = (char*)take(4096ull * 3072 * 2);
  unsigned short* Qb = (unsigned short*)big;
  unsigned short* Kb = (unsigned short*)(big + 4096ull * 768 * 2);      // frag-major
  unsigned short* Vb = (unsigned short*)(big + 2ull * 4096 * 768 * 2);  // frag-major
  unsigned short* a2 = (unsigned short*)big;
  unsigned short* part = (unsigned short*)take(4ull * 4096 * 768 * 2);  // bf16 partials
  float* Mb_         = (float*)take(2ull * 49152 * 4);
  float* Lb_         = (float*)take(2ull * 49152 * 4);
  const bool can_split = off <= ws_size;

  prep<<<11008, 256, 0, stream>>>(qkv_w, proj_w, fc1_w, fc2_w, wq, wp, w1, w2,
                                  x, ln1_w, ln1_b, h);
  gemm_nt<0><<<dim3(18, 32), 256, 0, stream>>>(h, wq, qkv_b, nullptr, Qb, Kb, Vb, 4096, 2304, 768, 768);

  if (can_split) {
    attn_fwd<1><<<dim3(32, 24, 2), 256, 0, stream>>>(Qb, Kb, Vb, nullptr, part, Mb_, Lb_);
    attn_combine<<<3072, 256, 0, stream>>>(part, Mb_, Lb_, h);
  } else {
    attn_fwd<0><<<dim3(32, 24), 256, 0, stream>>>(Qb, Kb, Vb, h, nullptr, nullptr, nullptr);
  }

  if (can_split) {
    gemm_nt<4><<<dim3(6, 32, 2), 256, 0, stream>>>(h, wp, nullptr, nullptr, part, nullptr, nullptr, 4096, 768, 384, 768);
    reduce_ln2<<<4096, 256, 0, stream>>>(part, proj_b, x, ln2_w, ln2_b, x2, h);
  } else {
    gemm_nt<1><<<dim3(6, 32), 256, 0, stream>>>(h, wp, proj_b, x, x2, nullptr, nullptr, 4096, 768, 768, 768);
    ln_kernel<<<4096, 256, 0, stream>>>(x2, ln2_w, ln2_b, h);
  }

  gemm_nt<2><<<dim3(24, 32), 256, 0, stream>>>(h, w1, fc1_b, nullptr, a2, nullptr, nullptr, 4096, 3072, 768, 768);

  if (can_split) {
    gemm_nt<4><<<dim3(6, 32, 4), 256, 0, stream>>>(a2, w2, nullptr, nullptr, part, nullptr, nullptr, 4096, 768, 768, 3072);
    reduce_k<4><<<3072, 256, 0, stream>>>(part, fc2_b, x2, (float*)d_out);
  } else {
    gemm_nt<3><<<dim3(6, 32), 256, 0, stream>>>(a2, w2, fc2_b, x2, d_out, nullptr, nullptr, 4096, 768, 3072, 3072);
  }
}